// Round 4
// baseline (151.304 us; speedup 1.0000x reference)
//
#include <hip/hip_runtime.h>
#include <cstdint>

#define B_NODES 16384
#define C_CH    64
#define I_DIM   9
#define S_SPEC  10
#define K3C     23
#define K2C     5
#define K1C     2
#define NTRI    165   // unique triples p<=q<=r in [0,9)
#define NPAIR   45    // unique pairs p<=q
#define NSING   9
#define NIDX    (NTRI + NPAIR + NSING)   // 219
#define TILE_N  256   // nodes per tile (= block)
#define CH_G    4     // channels per block
#define NGRP    (C_CH / CH_G)            // 16
#define MAXT    74    // <= B/256 + S
#define SCAP    (MAXT * TILE_N)
#define OUT_STRIDE (4 * C_CH)

#define N3SL (NTRI * K3C)    // 3795
#define N2SL (NPAIR * K2C)   // 225
#define N1SL (NSING * K1C)   // 18
#define NUSYM (N3SL + N2SL + N1SL)  // 4038

typedef float v2f  __attribute__((ext_vector_type(2)));
typedef float v16f __attribute__((ext_vector_type(16)));

// ============ kernel 1: prep (block 0: hist+plan+init; blocks 1..: usym) ============

__global__ __launch_bounds__(256) void k_prep(
        const float* __restrict__ y,
        const float* __restrict__ U3s, const float* __restrict__ U2s,
        const float* __restrict__ U1s,
        const float* __restrict__ U3v, const float* __restrict__ U2v,
        const float* __restrict__ U1v,
        int* __restrict__ species, int* __restrict__ seg_start,
        int* __restrict__ cursor, int* __restrict__ tilesp, int* __restrict__ sorted,
        float* __restrict__ us3, float* __restrict__ uv3,
        float* __restrict__ us2, float* __restrict__ uv2,
        float* __restrict__ us1, float* __restrict__ uv1) {
    int tid = threadIdx.x;
    if (blockIdx.x == 0) {
        __shared__ int hcnt[S_SPEC];
        if (tid < S_SPEC) hcnt[tid] = 0;
        __syncthreads();
        for (int i = tid; i < B_NODES; i += 256) {
            int e = 0; float best = -1.f;
            #pragma unroll
            for (int j = 0; j < S_SPEC; ++j) {
                float v = y[i * S_SPEC + j];
                if (v > best) { best = v; e = j; }
            }
            species[i] = e;
            atomicAdd(&hcnt[e], 1);
        }
        for (int i = tid; i < SCAP; i += 256) sorted[i] = -1;
        for (int i = tid; i < MAXT; i += 256) tilesp[i] = -1;
        __syncthreads();
        if (tid == 0) {
            int run = 0;
            for (int e = 0; e < S_SPEC; ++e) {
                seg_start[e] = run;
                cursor[e] = 0;
                int tiles = (hcnt[e] + TILE_N - 1) / TILE_N;
                for (int t = 0; t < tiles; ++t) tilesp[run / TILE_N + t] = e;
                run += tiles * TILE_N;
            }
        }
        return;
    }
    // ---- usym blocks ----
    int t = (blockIdx.x - 1) * 256 + tid;
    if (t >= NUSYM) return;

    if (t < N3SL) {
        int idx = t / K3C, k = t % K3C;
        int p = 0, q = 0, r = 0, cum = 0;
        for (int p0 = 0; p0 < 9; ++p0)
            for (int q0 = p0; q0 < 9; ++q0)
                for (int r0 = q0; r0 < 9; ++r0) {
                    if (cum == idx) { p = p0; q = q0; r = r0; }
                    ++cum;
                }
        int perm[6][3] = {{p,q,r},{p,r,q},{q,p,r},{q,r,p},{r,p,q},{r,q,p}};
        float a0 = 0.f, a1 = 0.f, a2 = 0.f, a3 = 0.f;
        for (int j = 0; j < 6; ++j) {
            bool dup = false;
            for (int j2 = 0; j2 < j; ++j2)
                if (perm[j2][0]==perm[j][0] && perm[j2][1]==perm[j][1] && perm[j2][2]==perm[j][2])
                    dup = true;
            if (dup) continue;
            int a = perm[j][0], bb = perm[j][1], i = perm[j][2];
            int off = ((a * 9 + bb) * 9 + i) * K3C + k;
            a0 += U3s[off];
            a1 += U3v[0 * 729 * K3C + off];
            a2 += U3v[1 * 729 * K3C + off];
            a3 += U3v[2 * 729 * K3C + off];
        }
        us3[t] = a0;
        uv3[0 * N3SL + t] = a1;
        uv3[1 * N3SL + t] = a2;
        uv3[2 * N3SL + t] = a3;
    } else if (t < N3SL + N2SL) {
        int t2 = t - N3SL;
        int idx = t2 / K2C, k = t2 % K2C;
        int p = 0, q = 0, cum = 0;
        for (int p0 = 0; p0 < 9; ++p0)
            for (int q0 = p0; q0 < 9; ++q0) {
                if (cum == idx) { p = p0; q = q0; }
                ++cum;
            }
        int np = (p == q) ? 1 : 2;
        int pa[2] = {p, q}, pb[2] = {q, p};
        float a0 = 0.f, a1 = 0.f, a2 = 0.f, a3 = 0.f;
        for (int j = 0; j < np; ++j) {
            int off = (pa[j] * 9 + pb[j]) * K2C + k;
            a0 += U2s[off];
            a1 += U2v[0 * 81 * K2C + off];
            a2 += U2v[1 * 81 * K2C + off];
            a3 += U2v[2 * 81 * K2C + off];
        }
        us2[t2] = a0;
        uv2[0 * N2SL + t2] = a1;
        uv2[1 * N2SL + t2] = a2;
        uv2[2 * N2SL + t2] = a3;
    } else {
        int t1 = t - N3SL - N2SL;   // p*K1C + k
        us1[t1] = U1s[t1];
        uv1[0 * N1SL + t1] = U1v[0 * 9 * K1C + t1];
        uv1[1 * N1SL + t1] = U1v[1 * 9 * K1C + t1];
        uv1[2 * N1SL + t1] = U1v[2 * 9 * K1C + t1];
    }
}

// ============ kernel 2: mid (blocks 0..63: scatter; rest: table build) ============
// table[((e*NGRP+g)*NIDX + row)*16 + ci*4 + m]   (64 B per row, coalesced writes)

__global__ __launch_bounds__(256) void k_mid(
        const int* __restrict__ species, const int* __restrict__ seg_start,
        int* __restrict__ cursor, int* __restrict__ sorted,
        const float* __restrict__ W3s, const float* __restrict__ W2s,
        const float* __restrict__ W1s,
        const float* __restrict__ W3v, const float* __restrict__ W2v,
        const float* __restrict__ W1v,
        const float* __restrict__ us3, const float* __restrict__ uv3,
        const float* __restrict__ us2, const float* __restrict__ uv2,
        const float* __restrict__ us1, const float* __restrict__ uv1,
        float* __restrict__ table) {
    int tid = threadIdx.x;
    if (blockIdx.x < B_NODES / 256) {
        // ---- scatter ----
        int b = blockIdx.x * 256 + tid;
        int e = species[b];
        int lane = tid & 63;
        unsigned long long lanebit = 1ull << lane;
        for (int j = 0; j < S_SPEC; ++j) {
            unsigned long long m = __ballot(e == j);
            if (m == 0ull) continue;
            int leader = __ffsll(m) - 1;
            int base = 0;
            if (lane == leader) base = atomicAdd(&cursor[j], __popcll(m));
            base = __shfl(base, leader);
            if (e == j) {
                int pos = base + __popcll(m & (lanebit - 1ull));
                sorted[seg_start[j] + pos] = b;
            }
        }
        return;
    }
    // ---- table build ----
    int t = (blockIdx.x - B_NODES / 256) * 256 + tid;   // < 10*16*219*16 = 560640
    int j   = t & 15;
    int row = (t >> 4) % NIDX;
    int eg  = t / (16 * NIDX);
    int g = eg % NGRP, e = eg / NGRP;
    int ci = j >> 2, m = j & 3;
    int c = g * CH_G + ci;

    const float* Wp; const float* up; int K;
    if (row < NTRI) {
        K = K3C;
        Wp = ((m == 0) ? W3s : W3v) + (size_t)e * K3C * C_CH + c;
        up = (m == 0) ? (us3 + row * K3C) : (uv3 + (size_t)(m - 1) * N3SL + row * K3C);
    } else if (row < NTRI + NPAIR) {
        int r2 = row - NTRI;
        K = K2C;
        Wp = ((m == 0) ? W2s : W2v) + (size_t)e * K2C * C_CH + c;
        up = (m == 0) ? (us2 + r2 * K2C) : (uv2 + (size_t)(m - 1) * N2SL + r2 * K2C);
    } else {
        int r1 = row - NTRI - NPAIR;
        K = K1C;
        Wp = ((m == 0) ? W1s : W1v) + (size_t)e * K1C * C_CH + c;
        up = (m == 0) ? (us1 + r1 * K1C) : (uv1 + (size_t)(m - 1) * N1SL + r1 * K1C);
    }
    float acc = 0.f;
    for (int k = 0; k < K; ++k) acc += up[k] * Wp[k * C_CH];
    table[t] = acc;
}

// ============ kernel 3: main polynomial evaluation ============
// Block = 256 thr = 256 same-species nodes x 4 channels. All 4 waves consume
// the SAME uniform table stream (one s_load_dwordx16 per monomial row feeding
// 4 channels x 4 outputs) -> scalar-cache friendly, 12 VALU per 64B row.

__global__ __launch_bounds__(256, 4) void k_main(
        const float* __restrict__ x, const float* __restrict__ table,
        const int* __restrict__ sorted, const int* __restrict__ tilesp,
        float* __restrict__ out) {
    __shared__ float xs[TILE_N * 37];   // 36 floats/node, pad->37 (gcd(37,32)=1)

    int t = blockIdx.x, g = blockIdx.y;
    int e = tilesp[t];
    if (e < 0) return;
    int tid = threadIdx.x;

    // ---- stage x: per node 144B contiguous (4ch x 9 floats) ----
    for (int s = tid; s < TILE_N * 9; s += 256) {
        int n = s / 9, jj = s % 9;
        int b = sorted[t * TILE_N + n];
        float4 v = make_float4(0.f, 0.f, 0.f, 0.f);
        if (b >= 0)
            v = *(const float4*)(x + (size_t)b * (C_CH * I_DIM) + g * (CH_G * I_DIM) + jj * 4);
        xs[n * 37 + jj * 4 + 0] = v.x;
        xs[n * 37 + jj * 4 + 1] = v.y;
        xs[n * 37 + jj * 4 + 2] = v.z;
        xs[n * 37 + jj * 4 + 3] = v.w;
    }
    __syncthreads();

    float xr[CH_G][9];
    #pragma unroll
    for (int ch = 0; ch < CH_G; ++ch)
        #pragma unroll
        for (int i = 0; i < 9; ++i)
            xr[ch][i] = xs[tid * 37 + ch * 9 + i];

    const v16f* __restrict__ T = (const v16f*)table
        + (size_t)__builtin_amdgcn_readfirstlane(e * NGRP + g) * NIDX;

    v2f a01[CH_G], a23[CH_G];
    #pragma unroll
    for (int ch = 0; ch < CH_G; ++ch) {
        a01[ch] = (v2f){0.f, 0.f};
        a23[ch] = (v2f){0.f, 0.f};
    }

    int ti = 0, pi = 0;
    #pragma unroll
    for (int p = 0; p < 9; ++p) {
        {
            v16f rs = T[NTRI + NPAIR + p];
            #pragma unroll
            for (int ch = 0; ch < CH_G; ++ch) {
                a01[ch] += (v2f){rs[ch*4+0], rs[ch*4+1]} * xr[ch][p];
                a23[ch] += (v2f){rs[ch*4+2], rs[ch*4+3]} * xr[ch][p];
            }
        }
        #pragma unroll
        for (int q = p; q < 9; ++q) {
            float m2[CH_G];
            #pragma unroll
            for (int ch = 0; ch < CH_G; ++ch) m2[ch] = xr[ch][p] * xr[ch][q];
            v16f rp = T[NTRI + pi];
            #pragma unroll
            for (int ch = 0; ch < CH_G; ++ch) {
                a01[ch] += (v2f){rp[ch*4+0], rp[ch*4+1]} * m2[ch];
                a23[ch] += (v2f){rp[ch*4+2], rp[ch*4+3]} * m2[ch];
            }
            ++pi;
            #pragma unroll
            for (int r = q; r < 9; ++r) {
                v16f rt = T[ti];
                #pragma unroll
                for (int ch = 0; ch < CH_G; ++ch) {
                    float m3 = m2[ch] * xr[ch][r];
                    a01[ch] += (v2f){rt[ch*4+0], rt[ch*4+1]} * m3;
                    a23[ch] += (v2f){rt[ch*4+2], rt[ch*4+3]} * m3;
                }
                ++ti;
            }
        }
    }

    int b = sorted[t * TILE_N + tid];
    if (b < 0) return;
    float* o = out + (size_t)b * OUT_STRIDE;
    // scalar part: channels g*4 .. g*4+3 (16B aligned)
    *(float4*)(o + g * CH_G) = make_float4(a01[0].x, a01[1].x, a01[2].x, a01[3].x);
    // vector part: out[64 + c*3 + m'], 12 contiguous floats (48B, 16B aligned)
    float vv[12];
    #pragma unroll
    for (int ch = 0; ch < CH_G; ++ch) {
        vv[ch*3+0] = a01[ch].y;
        vv[ch*3+1] = a23[ch].x;
        vv[ch*3+2] = a23[ch].y;
    }
    float* ov = o + C_CH + g * (3 * CH_G);
    *(float4*)(ov + 0) = make_float4(vv[0], vv[1], vv[2],  vv[3]);
    *(float4*)(ov + 4) = make_float4(vv[4], vv[5], vv[6],  vv[7]);
    *(float4*)(ov + 8) = make_float4(vv[8], vv[9], vv[10], vv[11]);
}

// ============ launcher ============

extern "C" void kernel_launch(void* const* d_in, const int* in_sizes, int n_in,
                              void* d_out, int out_size, void* d_ws, size_t ws_size,
                              hipStream_t stream) {
    const float* x   = (const float*)d_in[0];
    const float* y   = (const float*)d_in[1];
    const float* U3s = (const float*)d_in[2];
    const float* U2s = (const float*)d_in[3];
    const float* U1s = (const float*)d_in[4];
    const float* W3s = (const float*)d_in[5];
    const float* W2s = (const float*)d_in[6];
    const float* W1s = (const float*)d_in[7];
    const float* U3v = (const float*)d_in[8];
    const float* U2v = (const float*)d_in[9];
    const float* U1v = (const float*)d_in[10];
    const float* W3v = (const float*)d_in[11];
    const float* W2v = (const float*)d_in[12];
    const float* W1v = (const float*)d_in[13];
    float* out = (float*)d_out;

    char* ws = (char*)d_ws;
    size_t off = 0;
    auto alloc = [&](size_t bytes) -> char* {
        char* p = ws + off;
        off = (off + bytes + 255) & ~(size_t)255;
        return p;
    };
    float* table   = (float*)alloc((size_t)S_SPEC * NGRP * NIDX * 16 * sizeof(float));
    float* us3     = (float*)alloc(N3SL * sizeof(float));
    float* uv3     = (float*)alloc(3 * N3SL * sizeof(float));
    float* us2     = (float*)alloc(N2SL * sizeof(float));
    float* uv2     = (float*)alloc(3 * N2SL * sizeof(float));
    float* us1     = (float*)alloc(N1SL * sizeof(float));
    float* uv1     = (float*)alloc(3 * N1SL * sizeof(float));
    int* sorted    = (int*)alloc(SCAP * sizeof(int));
    int* tilesp    = (int*)alloc(MAXT * sizeof(int));
    int* species   = (int*)alloc(B_NODES * sizeof(int));
    int* seg_start = (int*)alloc(S_SPEC * sizeof(int));
    int* cursor    = (int*)alloc(S_SPEC * sizeof(int));

    // kernel 1: hist + plan + init (block 0) and usym (blocks 1..16)
    int prep_blocks = 1 + (NUSYM + 255) / 256;
    hipLaunchKernelGGL(k_prep, dim3(prep_blocks), dim3(256), 0, stream,
                       y, U3s, U2s, U1s, U3v, U2v, U1v,
                       species, seg_start, cursor, tilesp, sorted,
                       us3, uv3, us2, uv2, us1, uv1);

    // kernel 2: scatter (64 blocks) + table build (2190 blocks)
    int table_threads = S_SPEC * NGRP * NIDX * 16;   // 560640
    int mid_blocks = B_NODES / 256 + table_threads / 256;
    hipLaunchKernelGGL(k_mid, dim3(mid_blocks), dim3(256), 0, stream,
                       species, seg_start, cursor, sorted,
                       W3s, W2s, W1s, W3v, W2v, W1v,
                       us3, uv3, us2, uv2, us1, uv1, table);

    // kernel 3: main
    hipLaunchKernelGGL(k_main, dim3(MAXT, NGRP), dim3(256), 0, stream,
                       x, table, sorted, tilesp, out);
}